// Round 14
// baseline (68.899 us; speedup 1.0000x reference)
//
#include <hip/hip_runtime.h>
#include <cstdint>

#define B_ 8
#define T_ 2048
#define C_ 1024
#define H_ 64
#define BT_ (B_ * T_)

typedef short short8 __attribute__((ext_vector_type(8)));
typedef short bh4 __attribute__((ext_vector_type(4)));
typedef float f32x4 __attribute__((ext_vector_type(4)));

__device__ inline short f2bf(float f) {
  uint32_t u = __float_as_uint(f);
  u += 0x7fffu + ((u >> 16) & 1u);  // RNE; inputs finite
  return (short)(u >> 16);
}

// async global->LDS, 16B per lane; LDS dest = uniform base + lane*16 (HW rule)
__device__ __forceinline__ void gl_lds16(const void* g, void* l) {
  __builtin_amdgcn_global_load_lds(
      (const __attribute__((address_space(1))) unsigned int*)g,
      (__attribute__((address_space(3))) unsigned int*)l, 16, 0, 0);
}

// volatile asm 16B load (used only for qa in the prologue, then drained —
// keeps compiler-owned VMEM out of the attn k-loop so our counted vmcnt
// is the only wait discipline).
#define ALOAD(dst, p)                                              \
  asm volatile("global_load_dwordx4 %0, %1, off"                   \
               : "=v"(dst) : "v"(p) : "memory")

// ---------------------------------------------------------------------------
// prep_w: Wk/Wq/Wv [1024][64] fp32 -> Wt [192][1024] bf16 (transposed).
// Folded into Wk: score scale 1024^-0.5 AND log2(e) (softmax in log2 domain).
// ---------------------------------------------------------------------------
__global__ __launch_bounds__(256) void prep_w(
    const float* __restrict__ Wk, const float* __restrict__ Wq,
    const float* __restrict__ Wv, short* __restrict__ Wt) {
  __shared__ float wl[64][68];
  const int mat = blockIdx.x >> 4;
  const int kc = blockIdx.x & 15;
  const float* W = (mat == 0) ? Wk : (mat == 1) ? Wq : Wv;
  const float sc = (mat == 0) ? 0.03125f * 1.44269504088896f : 1.0f;
  const int t = threadIdx.x;
  const int k0 = kc * 64;
#pragma unroll
  for (int j = 0; j < 4; ++j) {
    int s = t + 256 * j;
    int kr = s >> 4, cf = s & 15;
    float4 v = *reinterpret_cast<const float4*>(&W[(size_t)(k0 + kr) * H_ + cf * 4]);
    wl[kr][cf * 4 + 0] = v.x; wl[kr][cf * 4 + 1] = v.y;
    wl[kr][cf * 4 + 2] = v.z; wl[kr][cf * 4 + 3] = v.w;
  }
  __syncthreads();
#pragma unroll
  for (int j = 0; j < 2; ++j) {
    int s = t + 256 * j;
    int n = s >> 3, g = s & 7;
    short8 o;
#pragma unroll
    for (int i = 0; i < 8; ++i) o[i] = f2bf(wl[8 * g + i][n] * sc);
    *reinterpret_cast<short8*>(&Wt[(size_t)(mat * 64 + n) * C_ + k0 + 8 * g]) = o;
  }
}

// ---------------------------------------------------------------------------
// proj: m97-style GEMM (unchanged, ~15us). 512 blocks x 128 thr.
// ---------------------------------------------------------------------------
__global__ __launch_bounds__(128, 1) void proj_kernel(
    const float* __restrict__ x, const short* __restrict__ Wt,
    short* __restrict__ Kp, short* __restrict__ Qp, short* __restrict__ Vt) {
  __shared__ float xs[2][32 * 64];
  __shared__ short ws[2][192 * 64];
  const int t = threadIdx.x;
  const int w = t >> 6, lane = t & 63;
  const int l15 = lane & 15, lg = lane >> 4;
  const int rowBase = blockIdx.x * 32;

  f32x4 acc[12];
  const f32x4 zf = {0.f, 0.f, 0.f, 0.f};
#pragma unroll
  for (int i = 0; i < 12; ++i) acc[i] = zf;

  auto stage = [&](int buf, int k0) {
#pragma unroll
    for (int j = 0; j < 4; ++j) {
      const int seg = w * 4 + j;
      const int r = seg * 4 + (lane >> 4);
      const float* g =
          &x[(size_t)(rowBase + r) * C_ + k0 + (((lane & 15) ^ (r & 7)) << 2)];
      gl_lds16(g, (char*)&xs[buf][0] + seg * 1024);
    }
#pragma unroll
    for (int j = 0; j < 12; ++j) {
      const int seg = w * 12 + j;
      const int n = seg * 8 + (lane >> 3);
      const short* g =
          &Wt[(size_t)n * C_ + k0 + (((lane & 7) ^ (n & 7)) << 3)];
      gl_lds16(g, (char*)&ws[buf][0] + seg * 1024);
    }
  };

  stage(0, 0);

#pragma unroll 1
  for (int it = 0; it < 16; ++it) {
    __syncthreads();
    const int cb = it & 1;
    if (it < 15) stage(cb ^ 1, (it + 1) * 64);
    const int arow = 16 * w + l15;
    const int x7 = arow & 7;
    const float* xrow = &xs[cb][arow * 64];
    float4 fa = *reinterpret_cast<const float4*>(xrow + (((2 * lg) ^ x7) << 2));
    float4 fb = *reinterpret_cast<const float4*>(xrow + (((2 * lg + 1) ^ x7) << 2));
    float4 fc = *reinterpret_cast<const float4*>(xrow + (((2 * lg + 8) ^ x7) << 2));
    float4 fd = *reinterpret_cast<const float4*>(xrow + (((2 * lg + 9) ^ x7) << 2));
    short8 a0, a1;
    a0[0] = f2bf(fa.x); a0[1] = f2bf(fa.y); a0[2] = f2bf(fa.z); a0[3] = f2bf(fa.w);
    a0[4] = f2bf(fb.x); a0[5] = f2bf(fb.y); a0[6] = f2bf(fb.z); a0[7] = f2bf(fb.w);
    a1[0] = f2bf(fc.x); a1[1] = f2bf(fc.y); a1[2] = f2bf(fc.z); a1[3] = f2bf(fc.w);
    a1[4] = f2bf(fd.x); a1[5] = f2bf(fd.y); a1[6] = f2bf(fd.z); a1[7] = f2bf(fd.w);
#pragma unroll
    for (int nt = 0; nt < 12; ++nt) {
      const int n2 = 16 * nt + l15, n7 = n2 & 7;
      const short* wrow = &ws[cb][n2 * 64];
      short8 b0 = *reinterpret_cast<const short8*>(wrow + ((lg ^ n7) << 3));
      short8 b1 = *reinterpret_cast<const short8*>(wrow + (((4 + lg) ^ n7) << 3));
      acc[nt] = __builtin_amdgcn_mfma_f32_16x16x32_bf16(a0, b0, acc[nt], 0, 0, 0);
      acc[nt] = __builtin_amdgcn_mfma_f32_16x16x32_bf16(a1, b1, acc[nt], 0, 0, 0);
    }
  }

  const int strip = blockIdx.x * 2 + w;
  const int rb = strip * 16;
#pragma unroll
  for (int nt = 0; nt < 4; ++nt)
#pragma unroll
    for (int r = 0; r < 4; ++r) {
      const size_t orow = rb + lg * 4 + r;
      Kp[orow * H_ + nt * 16 + l15] = f2bf(acc[nt][r]);
      Qp[orow * H_ + nt * 16 + l15] = f2bf(acc[4 + nt][r]);
    }
  __syncthreads();
  short* vl = reinterpret_cast<short*>(&xs[0][0]) + w * (16 * 66);
#pragma unroll
  for (int nt = 0; nt < 4; ++nt)
#pragma unroll
    for (int r = 0; r < 4; ++r)
      vl[(lg * 4 + r) * 66 + nt * 16 + l15] = f2bf(acc[8 + nt][r]);
  asm volatile("s_waitcnt lgkmcnt(0)" ::: "memory");
  short8 o0, o1;
#pragma unroll
  for (int i = 0; i < 8; ++i) o0[i] = vl[i * 66 + lane];
#pragma unroll
  for (int i = 0; i < 8; ++i) o1[i] = vl[(8 + i) * 66 + lane];
  const int bb = strip >> 7, tb = (strip & 127) * 16;
  short* dst = &Vt[((size_t)bb * H_ + lane) * T_ + tb];
  *reinterpret_cast<short8*>(dst) = o0;
  *reinterpret_cast<short8*>(dst + 8) = o1;
}

// ---------------------------------------------------------------------------
// attn: causal flash attention, swapped-operand bf16 MFMA, WAVE-PRIVATE
// barrier-free pipeline. 1024 blocks (batch x 16-row q-tile, big-first) x
// 256 thr (4 waves), k-split x4 (wave s: kt = s, s+4, ...), KVBLK=64.
// Each wave stages its own K/V tile into PRIVATE LDS double-buffers via
// global_load_lds (16 loads of 8 contiguous 128B rows) and synchronizes with
// inline-asm s_waitcnt vmcnt(16) only — never 0 mid-loop, no __syncthreads
// in the loop (nothing shared). Fixes the ~3k cy/period barrier-convoy cost
// of R12/R13 while keeping un-sinkable contiguous staging.
// LDS: 4 waves x (16KB K + 16KB V dbuf) + 8KB P = 136KB -> 1 block/CU.
// ---------------------------------------------------------------------------
__global__ __launch_bounds__(256, 1) void attn_kernel(
    const short* __restrict__ Kq, const short* __restrict__ Qk,
    const short* __restrict__ Vt, float* __restrict__ out) {
  __shared__ short Ks[4][2][64 * 64];  // [wave][buf][kv=64][h=64]
  __shared__ short Vs[4][2][64 * 64];  // [wave][buf][d=64][kv=64]
  __shared__ short Ps[4][16 * 64];     // per-wave P^T staging
  const int t = threadIdx.x, s = t >> 6, lane = t & 63;
  const int l15 = lane & 15, lg = lane >> 4;
  const int batch = blockIdx.x & 7;
  const int u = 127 - (blockIdx.x >> 3);  // 16-row q-tile, biggest first
  const short* Kb = Kq + (size_t)batch * T_ * H_;
  const short* Qb = Qk + (size_t)batch * T_ * H_;
  const short* Vb = Vt + (size_t)batch * H_ * T_;
  float* ob = out + (size_t)batch * T_ * H_;
  short* ps = &Ps[s][0];
  const f32x4 zf = {0.f, 0.f, 0.f, 0.f};
  const int m7 = (l15 & 7) << 3;
  const int k7 = l15 & 7;

  const int qbase = u * 16;
  // qa via asm loads + full drain BEFORE staging starts (no compiler VMEM in loop)
  short8 qa0, qa1;
  {
    const short* qp = &Kb[(size_t)(qbase + l15) * H_ + lg * 8];
    ALOAD(qa0, qp);
    ALOAD(qa1, qp + 32);
    asm volatile("s_waitcnt vmcnt(0)" ::: "memory");
    __builtin_amdgcn_sched_barrier(0);
  }
  f32x4 O[4];
#pragma unroll
  for (int i = 0; i < 4; ++i) O[i] = zf;
  float m = -1e30f, l = 0.f;
  const int nkt = (u >> 2) + 1;
  const int cnt = (s < nkt) ? ((nkt - 1 - s) >> 2) + 1 : 0;
  int kt = s;

  // wave-private staging: K tile 64 rows x 128B (8 loads of 8 rows),
  // V tile 64 rows x 128B (8 loads). Source col-XOR pre-swizzled, LDS linear.
  const int srow = lane >> 3;                 // row within an 8-row group
  const int scol = ((lane & 7) ^ srow) << 3;  // swizzled short offset in row
  auto stage = [&](int buf, int kb) {
    char* kd = (char*)&Ks[s][buf][0];
    char* vd = (char*)&Vs[s][buf][0];
#pragma unroll
    for (int g2 = 0; g2 < 8; ++g2)
      gl_lds16(&Qb[(size_t)(kb + g2 * 8 + srow) * H_ + scol], kd + g2 * 1024);
#pragma unroll
    for (int g2 = 0; g2 < 8; ++g2)
      gl_lds16(&Vb[(size_t)(g2 * 8 + srow) * T_ + kb + scol], vd + g2 * 1024);
  };

  if (cnt > 0) stage(0, kt * 64);

#pragma unroll 1
  for (int i = 0; i < cnt; ++i) {
    const int cb = i & 1;
    const int kbase = kt * 64;
    // issue next tile into the other buffer, then wait for CURRENT tile only
    if (i + 1 < cnt) {
      stage(cb ^ 1, (kt + 4) * 64);
      asm volatile("s_waitcnt vmcnt(16)" ::: "memory");  // prev 16 done; 16 fly
    } else {
      asm volatile("s_waitcnt vmcnt(0)" ::: "memory");   // last tile: drain
    }
    __builtin_amdgcn_sched_barrier(0);

    // QK^T swapped: S^T[k][q]; lane (q=l15) reg r of tile nt = key 16nt+4lg+r
    const short* kbuf = &Ks[s][cb][0];
    f32x4 S[4];
    __builtin_amdgcn_s_setprio(1);
#pragma unroll
    for (int nt = 0; nt < 4; ++nt) {
      S[nt] = zf;
      const short* krow = &kbuf[(16 * nt + l15) * 64];
      short8 kf0 = *reinterpret_cast<const short8*>(&krow[(lg ^ k7) << 3]);
      short8 kf1 = *reinterpret_cast<const short8*>(&krow[((4 + lg) ^ k7) << 3]);
      S[nt] = __builtin_amdgcn_mfma_f32_16x16x32_bf16(kf0, qa0, S[nt], 0, 0, 0);
      S[nt] = __builtin_amdgcn_mfma_f32_16x16x32_bf16(kf1, qa1, S[nt], 0, 0, 0);
    }
    __builtin_amdgcn_s_setprio(0);
    // causal mask (diagonal tile only)
    if (kt == nkt - 1) {
#pragma unroll
      for (int nt = 0; nt < 4; ++nt) {
        const int klo = kbase + 16 * nt + 4 * lg;
#pragma unroll
        for (int r = 0; r < 4; ++r)
          if (klo + r > qbase + l15) S[nt][r] = -1e30f;
      }
    }
    // per-lane online softmax (in-lane tree + 2 shfl)
    float mx0 = fmaxf(fmaxf(S[0][0], S[0][1]), fmaxf(S[0][2], S[0][3]));
    float mx1 = fmaxf(fmaxf(S[1][0], S[1][1]), fmaxf(S[1][2], S[1][3]));
    float mx2 = fmaxf(fmaxf(S[2][0], S[2][1]), fmaxf(S[2][2], S[2][3]));
    float mx3 = fmaxf(fmaxf(S[3][0], S[3][1]), fmaxf(S[3][2], S[3][3]));
    float mx = fmaxf(fmaxf(mx0, mx1), fmaxf(mx2, mx3));
    mx = fmaxf(mx, __shfl_xor(mx, 16));
    mx = fmaxf(mx, __shfl_xor(mx, 32));
    const float mn = fmaxf(m, mx);
    const float scv = exp2f(m - mn);
    m = mn;
    float rs = 0.f;
#pragma unroll
    for (int nt = 0; nt < 4; ++nt)
#pragma unroll
      for (int r = 0; r < 4; ++r) {
        const float pv = exp2f(S[nt][r] - mn);
        S[nt][r] = pv;
        rs += pv;
      }
    rs += __shfl_xor(rs, 16);
    rs += __shfl_xor(rs, 32);
    l = l * scv + rs;
#pragma unroll
    for (int nt = 0; nt < 4; ++nt) O[nt] *= scv;
    // P^T -> per-wave LDS [q=l15][k], XOR-swizzled (proven 0-conflict)
#pragma unroll
    for (int nt = 0; nt < 4; ++nt) {
      bh4 pk;
      pk[0] = f2bf(S[nt][0]); pk[1] = f2bf(S[nt][1]);
      pk[2] = f2bf(S[nt][2]); pk[3] = f2bf(S[nt][3]);
      *reinterpret_cast<bh4*>(&ps[l15 * 64 + ((16 * nt + 4 * lg) ^ m7)]) = pk;
    }
    // PV: O^T += V^T x P^T
    const short* vbuf = &Vs[s][cb][0];
    __builtin_amdgcn_s_setprio(1);
#pragma unroll
    for (int kc = 0; kc < 2; ++kc) {
      const short8 pa = *reinterpret_cast<const short8*>(
          &ps[l15 * 64 + ((32 * kc + 8 * lg) ^ m7)]);
#pragma unroll
      for (int nt = 0; nt < 4; ++nt) {
        const short8 vf = *reinterpret_cast<const short8*>(
            &vbuf[(16 * nt + l15) * 64 + (((kc * 4 + lg) ^ k7) << 3)]);
        O[nt] = __builtin_amdgcn_mfma_f32_16x16x32_bf16(vf, pa, O[nt], 0, 0, 0);
      }
    }
    __builtin_amdgcn_s_setprio(0);
    kt += 4;
  }
  // drain any stray VMEM before cross-wave LDS reuse / s_endpgm
  asm volatile("s_waitcnt vmcnt(0)" ::: "memory");
  __builtin_amdgcn_sched_barrier(0);

  // ---- 4-way k-split combine (reuse dead stage LDS for Po/Ml) ----
  __syncthreads();
  float* Po = reinterpret_cast<float*>(&Ks[0][0][0]);   // [4][16][68] f32
  float* Mlp = reinterpret_cast<float*>(&Vs[0][0][0]);  // [4][16][2]  f32
#pragma unroll
  for (int nt = 0; nt < 4; ++nt)
    *reinterpret_cast<f32x4*>(&Po[(s * 16 + l15) * 68 + 16 * nt + 4 * lg]) = O[nt];
  if (lane < 16) {
    Mlp[(s * 16 + l15) * 2 + 0] = m;
    Mlp[(s * 16 + l15) * 2 + 1] = l;
  }
  __syncthreads();
  {
    const int row = t >> 4, c4 = t & 15;
    float M = fmaxf(fmaxf(Mlp[row * 2], Mlp[(16 + row) * 2]),
                    fmaxf(Mlp[(32 + row) * 2], Mlp[(48 + row) * 2]));
    float L = 0.f;
    f32x4 o = zf;
#pragma unroll
    for (int s2 = 0; s2 < 4; ++s2) {
      const float sc = exp2f(Mlp[(s2 * 16 + row) * 2] - M);
      L += Mlp[(s2 * 16 + row) * 2 + 1] * sc;
      const f32x4 po = *reinterpret_cast<const f32x4*>(&Po[(s2 * 16 + row) * 68 + c4 * 4]);
      o += po * sc;
    }
    const f32x4 res = o * (1.f / L);
    *reinterpret_cast<f32x4*>(&ob[(size_t)(qbase + row) * H_ + c4 * 4]) = res;
  }
}

extern "C" void kernel_launch(void* const* d_in, const int* in_sizes, int n_in,
                              void* d_out, int out_size, void* d_ws, size_t ws_size,
                              hipStream_t stream) {
  const float* x = (const float*)d_in[0];
  const float* Wk = (const float*)d_in[1];
  const float* Wq = (const float*)d_in[2];
  const float* Wv = (const float*)d_in[3];
  float* out = (float*)d_out;

  short* Kp = (short*)d_ws;                  // [BT][64] bf16 (queries: x@Wk, scale*log2e folded)
  short* Qp = Kp + (size_t)BT_ * H_;         // [BT][64] bf16 (keys:    x@Wq)
  short* Vt = Qp + (size_t)BT_ * H_;         // [8][64][2048] bf16 (values^T)
  short* Wt = Vt + (size_t)BT_ * H_;         // [192][1024] bf16

  hipLaunchKernelGGL(prep_w, dim3(48), dim3(256), 0, stream, Wk, Wq, Wv, Wt);
  hipLaunchKernelGGL(proj_kernel, dim3(512), dim3(128), 0, stream, x, Wt, Kp, Qp, Vt);
  hipLaunchKernelGGL(attn_kernel, dim3(1024), dim3(256), 0, stream, Kp, Qp, Vt, out);
}

// Round 15
// 59.746 us; speedup vs baseline: 1.1532x; 1.1532x over previous
//
#include <hip/hip_runtime.h>
#include <cstdint>

#define B_ 8
#define T_ 2048
#define C_ 1024
#define H_ 64
#define BT_ (B_ * T_)

typedef short short8 __attribute__((ext_vector_type(8)));
typedef short bh4 __attribute__((ext_vector_type(4)));
typedef float f32x4 __attribute__((ext_vector_type(4)));

__device__ inline short f2bf(float f) {
  uint32_t u = __float_as_uint(f);
  u += 0x7fffu + ((u >> 16) & 1u);  // RNE; inputs finite
  return (short)(u >> 16);
}

// async global->LDS, 16B per lane; LDS dest = uniform base + lane*16 (HW rule)
__device__ __forceinline__ void gl_lds16(const void* g, void* l) {
  __builtin_amdgcn_global_load_lds(
      (const __attribute__((address_space(1))) unsigned int*)g,
      (__attribute__((address_space(3))) unsigned int*)l, 16, 0, 0);
}

// ---------------------------------------------------------------------------
// prep_w: Wk/Wq/Wv [1024][64] fp32 -> Wt [192][1024] bf16 (transposed).
// Folded into Wk: score scale 1024^-0.5 AND log2(e) (softmax in log2 domain).
// ---------------------------------------------------------------------------
__global__ __launch_bounds__(256) void prep_w(
    const float* __restrict__ Wk, const float* __restrict__ Wq,
    const float* __restrict__ Wv, short* __restrict__ Wt) {
  __shared__ float wl[64][68];
  const int mat = blockIdx.x >> 4;
  const int kc = blockIdx.x & 15;
  const float* W = (mat == 0) ? Wk : (mat == 1) ? Wq : Wv;
  const float sc = (mat == 0) ? 0.03125f * 1.44269504088896f : 1.0f;
  const int t = threadIdx.x;
  const int k0 = kc * 64;
#pragma unroll
  for (int j = 0; j < 4; ++j) {
    int s = t + 256 * j;
    int kr = s >> 4, cf = s & 15;
    float4 v = *reinterpret_cast<const float4*>(&W[(size_t)(k0 + kr) * H_ + cf * 4]);
    wl[kr][cf * 4 + 0] = v.x; wl[kr][cf * 4 + 1] = v.y;
    wl[kr][cf * 4 + 2] = v.z; wl[kr][cf * 4 + 3] = v.w;
  }
  __syncthreads();
#pragma unroll
  for (int j = 0; j < 2; ++j) {
    int s = t + 256 * j;
    int n = s >> 3, g = s & 7;
    short8 o;
#pragma unroll
    for (int i = 0; i < 8; ++i) o[i] = f2bf(wl[8 * g + i][n] * sc);
    *reinterpret_cast<short8*>(&Wt[(size_t)(mat * 64 + n) * C_ + k0 + 8 * g]) = o;
  }
}

// ---------------------------------------------------------------------------
// proj: m97-style GEMM, NOW 256 thr / 4 waves (2 waves/SIMD — the 128-thr
// version left every SIMD with ONE wave, so each barrier/vmcnt drain idled
// the SIMD; proj sat at ~25us vs 12us floor). 512 blocks, tile M=32 x N=192,
// K-step 64, dbuf LDS via global_load_lds (identical swizzle algebra).
// Wave = (row-group rg = w>>1 [16 rows], col-half ch = w&1 [96 cols, 6 acc]).
// ---------------------------------------------------------------------------
__global__ __launch_bounds__(256, 1) void proj_kernel(
    const float* __restrict__ x, const short* __restrict__ Wt,
    short* __restrict__ Kp, short* __restrict__ Qp, short* __restrict__ Vt) {
  __shared__ float xs[2][32 * 64];   // 8KB each
  __shared__ short ws[2][192 * 64];  // 24KB each
  const int t = threadIdx.x;
  const int w = t >> 6, lane = t & 63;
  const int l15 = lane & 15, lg = lane >> 4;
  const int rg = w >> 1, ch = w & 1;
  const int rowBase = blockIdx.x * 32;

  f32x4 acc[6];
  const f32x4 zf = {0.f, 0.f, 0.f, 0.f};
#pragma unroll
  for (int i = 0; i < 6; ++i) acc[i] = zf;

  auto stage = [&](int buf, int k0) {
#pragma unroll
    for (int j = 0; j < 2; ++j) {
      const int seg = w * 2 + j;  // 0..7 (x: 8 segs of 4 rows)
      const int r = seg * 4 + (lane >> 4);
      const float* g =
          &x[(size_t)(rowBase + r) * C_ + k0 + (((lane & 15) ^ (r & 7)) << 2)];
      gl_lds16(g, (char*)&xs[buf][0] + seg * 1024);
    }
#pragma unroll
    for (int j = 0; j < 6; ++j) {
      const int seg = w * 6 + j;  // 0..23 (W: 24 segs of 8 rows)
      const int n = seg * 8 + (lane >> 3);
      const short* g =
          &Wt[(size_t)n * C_ + k0 + (((lane & 7) ^ (n & 7)) << 3)];
      gl_lds16(g, (char*)&ws[buf][0] + seg * 1024);
    }
  };

  stage(0, 0);

#pragma unroll 1
  for (int it = 0; it < 16; ++it) {
    __syncthreads();
    const int cb = it & 1;
    if (it < 15) stage(cb ^ 1, (it + 1) * 64);
    const int arow = 16 * rg + l15;
    const int x7 = arow & 7;
    const float* xrow = &xs[cb][arow * 64];
    float4 fa = *reinterpret_cast<const float4*>(xrow + (((2 * lg) ^ x7) << 2));
    float4 fb = *reinterpret_cast<const float4*>(xrow + (((2 * lg + 1) ^ x7) << 2));
    float4 fc = *reinterpret_cast<const float4*>(xrow + (((2 * lg + 8) ^ x7) << 2));
    float4 fd = *reinterpret_cast<const float4*>(xrow + (((2 * lg + 9) ^ x7) << 2));
    short8 a0, a1;
    a0[0] = f2bf(fa.x); a0[1] = f2bf(fa.y); a0[2] = f2bf(fa.z); a0[3] = f2bf(fa.w);
    a0[4] = f2bf(fb.x); a0[5] = f2bf(fb.y); a0[6] = f2bf(fb.z); a0[7] = f2bf(fb.w);
    a1[0] = f2bf(fc.x); a1[1] = f2bf(fc.y); a1[2] = f2bf(fc.z); a1[3] = f2bf(fc.w);
    a1[4] = f2bf(fd.x); a1[5] = f2bf(fd.y); a1[6] = f2bf(fd.z); a1[7] = f2bf(fd.w);
#pragma unroll
    for (int nt = 0; nt < 6; ++nt) {
      const int n2 = 16 * (6 * ch + nt) + l15, n7 = n2 & 7;
      const short* wrow = &ws[cb][n2 * 64];
      short8 b0 = *reinterpret_cast<const short8*>(wrow + ((lg ^ n7) << 3));
      short8 b1 = *reinterpret_cast<const short8*>(wrow + (((4 + lg) ^ n7) << 3));
      acc[nt] = __builtin_amdgcn_mfma_f32_16x16x32_bf16(a0, b0, acc[nt], 0, 0, 0);
      acc[nt] = __builtin_amdgcn_mfma_f32_16x16x32_bf16(a1, b1, acc[nt], 0, 0, 0);
    }
  }

  // ---- epilogue ----
  const int strip = blockIdx.x * 2 + rg;
  const int rb = strip * 16;
#pragma unroll
  for (int nt = 0; nt < 6; ++nt) {
    const int ntg = 6 * ch + nt;  // global col-tile 0..11
    if (ntg < 8) {                // K (0-3) and Q (4-7) row-major stores
      short* O = (ntg < 4) ? Kp : Qp;
      const int col = (ntg & 3) * 16 + l15;
#pragma unroll
      for (int r = 0; r < 4; ++r)
        O[(size_t)(rb + lg * 4 + r) * H_ + col] = f2bf(acc[nt][r]);
    }
  }
  __syncthreads();  // xs dead; reuse for V transpose
  if (ch == 1) {    // waves 1,3 hold V tiles (ntg 8..11) for strips rg=0,1
    short* vl = reinterpret_cast<short*>(&xs[0][0]) + rg * (16 * 66);
#pragma unroll
    for (int nt = 2; nt < 6; ++nt)
#pragma unroll
      for (int r = 0; r < 4; ++r)
        vl[(lg * 4 + r) * 66 + (nt - 2) * 16 + l15] = f2bf(acc[nt][r]);
    asm volatile("s_waitcnt lgkmcnt(0)" ::: "memory");
    short8 o0, o1;
#pragma unroll
    for (int i = 0; i < 8; ++i) o0[i] = vl[i * 66 + lane];
#pragma unroll
    for (int i = 0; i < 8; ++i) o1[i] = vl[(8 + i) * 66 + lane];
    const int bb = strip >> 7, tb = (strip & 127) * 16;
    short* dst = &Vt[((size_t)bb * H_ + lane) * T_ + tb];
    *reinterpret_cast<short8*>(dst) = o0;
    *reinterpret_cast<short8*>(dst + 8) = o1;
  }
}

// ---------------------------------------------------------------------------
// attn: R12 structure verbatim (measured best: 63.5us total) + balanced CU
// pairing. 512 blocks x 256 thr (4 waves). g = bid>>3; s = g<32 ? 63-g : g-32
// so the two blocks sharing a CU slot sum to ~constant period counts (R12's
// monotonic mapping gave 10..24). Wave = (row-group rg=w>>1, k-parity p=w&1).
// Period = two 64-key K+V tiles staged via contiguous global_load_lds,
// double-buffered (72KB LDS -> 2 blocks/CU). Per-lane log2 softmax; 2-way
// parity combine in dead stage LDS.
// ---------------------------------------------------------------------------
__global__ __launch_bounds__(256) void attn_kernel(
    const short* __restrict__ Kq, const short* __restrict__ Qk,
    const short* __restrict__ Vt, float* __restrict__ out) {
  __shared__ short Ks[4][64 * 64];  // [(per&1)*2 + tile][kv][h]
  __shared__ short Vs[4][64 * 64];  // [same][d][kv]
  __shared__ short Ps[4][16 * 64];  // per-wave P^T staging
  const int t = threadIdx.x, w = t >> 6, lane = t & 63;
  const int l15 = lane & 15, lg = lane >> 4;
  const int batch = blockIdx.x & 7;
  const int g = blockIdx.x >> 3;                 // 0..63
  const int s = (g < 32) ? (63 - g) : (g - 32);  // balanced big/small pairing
  const int p = w & 1;                           // this wave's k-tile parity
  const int rg = w >> 1;                         // row group
  const short* Kb = Kq + (size_t)batch * T_ * H_;
  const short* Qb = Qk + (size_t)batch * T_ * H_;
  const short* Vb = Vt + (size_t)batch * H_ * T_;
  float* ob = out + (size_t)batch * T_ * H_;
  short* ps = &Ps[w][0];
  const f32x4 zf = {0.f, 0.f, 0.f, 0.f};
  const int m7 = (l15 & 7) << 3;
  const int k7 = l15 & 7;

  const int qbase = s * 32;
  const int qrow = qbase + rg * 16 + l15;
  const short8 qa0 = *reinterpret_cast<const short8*>(&Kb[(size_t)qrow * H_ + lg * 8]);
  const short8 qa1 = *reinterpret_cast<const short8*>(&Kb[(size_t)qrow * H_ + lg * 8 + 32]);
  const int nkt = (s >> 1) + 1;    // 64-key tiles
  const int np = (nkt + 1) >> 1;   // periods (2 tiles each)

  const int srow = lane >> 3;
  const int ssw = ((lane & 7) ^ srow) << 3;
  auto stage = [&](int per) {
    int tj = 2 * per + (w >> 1);
    if (tj >= nkt) tj = nkt - 1;
    const int buf = (per & 1) * 2 + (w >> 1);
    const int kbase = tj * 64;
    const int h4 = (w & 1) * 4;
#pragma unroll
    for (int g2 = 0; g2 < 4; ++g2) {
      const int gg = h4 + g2;
      gl_lds16(&Qb[(size_t)(kbase + gg * 8 + srow) * H_ + ssw],
               (char*)&Ks[buf][0] + gg * 1024);
      gl_lds16(&Vb[(size_t)(gg * 8 + srow) * T_ + kbase + ssw],
               (char*)&Vs[buf][0] + gg * 1024);
    }
  };

  f32x4 O[4];
#pragma unroll
  for (int i = 0; i < 4; ++i) O[i] = zf;
  float m = -1e30f, l = 0.f;

  stage(0);

#pragma unroll 1
  for (int j = 0; j < np; ++j) {
    __syncthreads();  // drains staged loads + guards buffer reuse
    if (j + 1 < np) stage(j + 1);
    const int kt = 2 * j + p;
    if (kt < nkt) {
      const int cb = (j & 1) * 2 + p;
      const int kbase = kt * 64;
      f32x4 S[4];
      __builtin_amdgcn_s_setprio(1);
#pragma unroll
      for (int nt = 0; nt < 4; ++nt) {
        S[nt] = zf;
        const short* krow = &Ks[cb][(16 * nt + l15) * 64];
        short8 kf0 = *reinterpret_cast<const short8*>(&krow[(lg ^ k7) << 3]);
        short8 kf1 = *reinterpret_cast<const short8*>(&krow[((4 + lg) ^ k7) << 3]);
        S[nt] = __builtin_amdgcn_mfma_f32_16x16x32_bf16(kf0, qa0, S[nt], 0, 0, 0);
        S[nt] = __builtin_amdgcn_mfma_f32_16x16x32_bf16(kf1, qa1, S[nt], 0, 0, 0);
      }
      __builtin_amdgcn_s_setprio(0);
      if (kt == nkt - 1) {
#pragma unroll
        for (int nt = 0; nt < 4; ++nt) {
          const int klo = kbase + 16 * nt + 4 * lg;
#pragma unroll
          for (int r = 0; r < 4; ++r)
            if (klo + r > qrow) S[nt][r] = -1e30f;
        }
      }
      float mx0 = fmaxf(fmaxf(S[0][0], S[0][1]), fmaxf(S[0][2], S[0][3]));
      float mx1 = fmaxf(fmaxf(S[1][0], S[1][1]), fmaxf(S[1][2], S[1][3]));
      float mx2 = fmaxf(fmaxf(S[2][0], S[2][1]), fmaxf(S[2][2], S[2][3]));
      float mx3 = fmaxf(fmaxf(S[3][0], S[3][1]), fmaxf(S[3][2], S[3][3]));
      float mx = fmaxf(fmaxf(mx0, mx1), fmaxf(mx2, mx3));
      mx = fmaxf(mx, __shfl_xor(mx, 16));
      mx = fmaxf(mx, __shfl_xor(mx, 32));
      const float mn = fmaxf(m, mx);
      const float scv = exp2f(m - mn);
      m = mn;
      float rs = 0.f;
#pragma unroll
      for (int nt = 0; nt < 4; ++nt)
#pragma unroll
        for (int r = 0; r < 4; ++r) {
          const float pv = exp2f(S[nt][r] - mn);
          S[nt][r] = pv;
          rs += pv;
        }
      rs += __shfl_xor(rs, 16);
      rs += __shfl_xor(rs, 32);
      l = l * scv + rs;
#pragma unroll
      for (int nt = 0; nt < 4; ++nt) O[nt] *= scv;
#pragma unroll
      for (int nt = 0; nt < 4; ++nt) {
        bh4 pk;
        pk[0] = f2bf(S[nt][0]); pk[1] = f2bf(S[nt][1]);
        pk[2] = f2bf(S[nt][2]); pk[3] = f2bf(S[nt][3]);
        *reinterpret_cast<bh4*>(&ps[l15 * 64 + ((16 * nt + 4 * lg) ^ m7)]) = pk;
      }
      __builtin_amdgcn_s_setprio(1);
#pragma unroll
      for (int kc = 0; kc < 2; ++kc) {
        const short8 pa = *reinterpret_cast<const short8*>(
            &ps[l15 * 64 + ((32 * kc + 8 * lg) ^ m7)]);
#pragma unroll
        for (int nt = 0; nt < 4; ++nt) {
          const short8 vf = *reinterpret_cast<const short8*>(
              &Vs[cb][(16 * nt + l15) * 64 + (((kc * 4 + lg) ^ k7) << 3)]);
          O[nt] = __builtin_amdgcn_mfma_f32_16x16x32_bf16(vf, pa, O[nt], 0, 0, 0);
        }
      }
      __builtin_amdgcn_s_setprio(0);
    }
  }

  // ---- 2-way parity combine (reuse dead stage LDS) ----
  __syncthreads();
  float* Po = reinterpret_cast<float*>(&Ks[0][0]);   // [4][16][68] f32
  float* Mlp = reinterpret_cast<float*>(&Ps[0][0]);  // [4][16][2]  f32
#pragma unroll
  for (int nt = 0; nt < 4; ++nt)
    *reinterpret_cast<f32x4*>(&Po[(w * 16 + l15) * 68 + 16 * nt + 4 * lg]) = O[nt];
  if (lane < 16) {
    Mlp[(w * 16 + l15) * 2 + 0] = m;
    Mlp[(w * 16 + l15) * 2 + 1] = l;
  }
  __syncthreads();
  {
    const int row = t >> 4, c4 = t & 15;
#pragma unroll
    for (int gg = 0; gg < 2; ++gg) {
      const int s0 = gg * 2, s1 = gg * 2 + 1;
      const float m0 = Mlp[(s0 * 16 + row) * 2], l0 = Mlp[(s0 * 16 + row) * 2 + 1];
      const float m1 = Mlp[(s1 * 16 + row) * 2], l1 = Mlp[(s1 * 16 + row) * 2 + 1];
      const float M = fmaxf(m0, m1);
      const float e0 = exp2f(m0 - M), e1 = exp2f(m1 - M);
      const float L = l0 * e0 + l1 * e1;
      const f32x4 o0 = *reinterpret_cast<const f32x4*>(&Po[(s0 * 16 + row) * 68 + c4 * 4]);
      const f32x4 o1 = *reinterpret_cast<const f32x4*>(&Po[(s1 * 16 + row) * 68 + c4 * 4]);
      const f32x4 res = (o0 * e0 + o1 * e1) * (1.f / L);
      *reinterpret_cast<f32x4*>(&ob[(size_t)(qbase + gg * 16 + row) * H_ + c4 * 4]) = res;
    }
  }
}

extern "C" void kernel_launch(void* const* d_in, const int* in_sizes, int n_in,
                              void* d_out, int out_size, void* d_ws, size_t ws_size,
                              hipStream_t stream) {
  const float* x = (const float*)d_in[0];
  const float* Wk = (const float*)d_in[1];
  const float* Wq = (const float*)d_in[2];
  const float* Wv = (const float*)d_in[3];
  float* out = (float*)d_out;

  short* Kp = (short*)d_ws;                  // [BT][64] bf16 (queries: x@Wk, scale*log2e folded)
  short* Qp = Kp + (size_t)BT_ * H_;         // [BT][64] bf16 (keys:    x@Wq)
  short* Vt = Qp + (size_t)BT_ * H_;         // [8][64][2048] bf16 (values^T)
  short* Wt = Vt + (size_t)BT_ * H_;         // [192][1024] bf16

  hipLaunchKernelGGL(prep_w, dim3(48), dim3(256), 0, stream, Wk, Wq, Wv, Wt);
  hipLaunchKernelGGL(proj_kernel, dim3(512), dim3(256), 0, stream, x, Wt, Kp, Qp, Vt);
  hipLaunchKernelGGL(attn_kernel, dim3(512), dim3(256), 0, stream, Kp, Qp, Vt, out);
}